// Round 4
// baseline (512.873 us; speedup 1.0000x reference)
//
#include <hip/hip_runtime.h>
#include <math.h>

#define B_    8
#define CIN_  64
#define COUT_ 64
#define Hs    96
#define Ws    96
#define KK    9
#define PLANE (Hs*Ws)        // 9216
#define IMG   (CIN_*PLANE)   // 589824
#define NP    (B_*PLANE)     // 73728
#define NBLK  (NP/64)        // 1152 blocks

// LDS float-index map (14016 floats = 56064 B total):
//  [0,8192)      phase A: weight half (32 KB)  /  phase B: smp dbuf [2][64][64]
//  [8192,9920)   om_s [27][64]
//  [9920,14016)  wls  [64][64] (tap weights, single buffer)
#define SMP_OFF 0
#define OM_OFF  8192
#define WLS_OFF 9920
#define LDS_FLOATS 14016

__device__ __forceinline__ int swz(int bid) { return (bid & 7) * (NBLK / 8) + (bid >> 3); }

// wT[(k*64+c)*64+o]            = weight[o*576 + c*9 + k]          (36864 floats)
// woA2[half*8192+g*2048+cc32*64+j] = w_off[(g*7+j/9)*576 + (half*32+cc32)*9 + j%9]  (16384 floats, padded)
__global__ void transpose_weights(const float* __restrict__ weight,
                                  const float* __restrict__ w_off,
                                  float* __restrict__ wT,
                                  float* __restrict__ woA2) {
    int i = blockIdx.x * 256 + threadIdx.x;
    if (i < COUT_ * CIN_ * KK) {
        int o = i & 63;
        int c = (i >> 6) & 63;
        int k = i >> 12;
        wT[i] = weight[o * 576 + c * 9 + k];
    }
    if (i < 16384) {
        int half = i >> 13;
        int rem  = i & 8191;
        int g    = rem >> 11;
        int cc32 = (rem >> 6) & 31;
        int j    = i & 63;
        int cc   = half * 32 + cc32;
        int ch_l = j / 9;
        int t    = j - ch_l * 9;
        int ch   = g * 7 + ch_l;
        float v = 0.f;
        if (j < 63 && ch < 27) v = w_off[ch * 576 + cc * 9 + t];
        woA2[i] = v;
    }
}

__global__ __launch_bounds__(256)
void deform_all(const float* __restrict__ x,
                const float* __restrict__ woA2,
                const float* __restrict__ b_off,
                const float* __restrict__ wT,
                const float* __restrict__ bias,
                float* __restrict__ out) {
    __shared__ float lds[LDS_FLOATS];
    int tid = threadIdx.x;
    int px  = tid & 63;
    int g   = __builtin_amdgcn_readfirstlane(tid >> 6);  // wave id (uniform)
    int pg  = swz(blockIdx.x) * 64 + px;
    int b = pg / PLANE;
    int r = pg - b * PLANE;
    int h = r / Ws;
    int w = r - h * Ws;
    const float* xb = x + b * IMG;

    // -------- Phase A: offset conv (64 -> 27), ch-split waves --------
    int   off[9];
    float msk[9];
#pragma unroll
    for (int i = 0; i < 3; ++i) {
        int yy = h - 1 + i;
        int yc = min(max(yy, 0), Hs - 1);
        bool vy = (yy >= 0) && (yy < Hs);
#pragma unroll
        for (int j = 0; j < 3; ++j) {
            int xx = w - 1 + j;
            int xc = min(max(xx, 0), Ws - 1);
            bool v = vy && (xx >= 0) && (xx < Ws);
            off[i * 3 + j] = yc * Ws + xc;
            msk[i * 3 + j] = v ? 1.f : 0.f;
        }
    }

    float o27[7];
#pragma unroll
    for (int l = 0; l < 7; ++l) o27[l] = 0.f;

#pragma unroll 1
    for (int half = 0; half < 2; ++half) {
        __syncthreads();   // previous half's LDS reads complete
        {   // stage 32 KB of A-weights
            const float4* src = (const float4*)(woA2 + half * 8192);
            float4* dst = (float4*)lds;
#pragma unroll
            for (int j = 0; j < 8; ++j) dst[tid + 256 * j] = src[tid + 256 * j];
        }
        __syncthreads();
#pragma unroll 2
        for (int ccl = 0; ccl < 32; ++ccl) {
            int cc = half * 32 + ccl;
            const float* xp = xb + cc * PLANE;
            float xv[9];
#pragma unroll
            for (int t = 0; t < 9; ++t) xv[t] = xp[off[t]] * msk[t];
            const float4* wb4 = (const float4*)&lds[(g * 32 + ccl) << 6];
            float wv[64];
#pragma unroll
            for (int j4 = 0; j4 < 16; ++j4) {
                float4 q = wb4[j4];   // broadcast ds_read_b128
                wv[4 * j4] = q.x; wv[4 * j4 + 1] = q.y; wv[4 * j4 + 2] = q.z; wv[4 * j4 + 3] = q.w;
            }
#pragma unroll
            for (int j = 0; j < 63; ++j)
                o27[j / 9] = fmaf(xv[j % 9], wv[j], o27[j / 9]);
        }
    }
    {   // write om to LDS (region disjoint from A-weights)
        int nch = (g < 3) ? 7 : 6;
        for (int l = 0; l < nch; ++l) {
            int ch = g * 7 + l;
            lds[OM_OFF + ch * 64 + px] = o27[l] + b_off[ch];
        }
    }

    // -------- Phase B: sampling + main conv, o-split waves --------
    float acc[16];
#pragma unroll
    for (int j = 0; j < 16; ++j) acc[j] = bias[g * 16 + j];

    auto stage_smp = [&](int k, int bufi) {
        float dy = lds[OM_OFF + (2 * k) * 64 + px];
        float dx = lds[OM_OFF + (2 * k + 1) * 64 + px];
        float mo = lds[OM_OFF + (18 + k) * 64 + px];
        float m  = 1.f / (1.f + __expf(-mo));
        float ys = (float)(h - 1 + k / 3) + dy;
        float xs = (float)(w - 1 + k % 3) + dx;
        float y0f = floorf(ys), x0f = floorf(xs);
        float ly = ys - y0f, lx = xs - x0f;
        float hy = 1.f - ly, hx = 1.f - lx;
        int y0 = (int)y0f, x0 = (int)x0f;
        int y1 = y0 + 1,  x1 = x0 + 1;
        bool vy0 = (y0 >= 0) && (y0 < Hs);
        bool vy1 = (y1 >= 0) && (y1 < Hs);
        bool vx0 = (x0 >= 0) && (x0 < Ws);
        bool vx1 = (x1 >= 0) && (x1 < Ws);
        float w00 = (vy0 && vx0) ? m * hy * hx : 0.f;
        float w01 = (vy0 && vx1) ? m * hy * lx : 0.f;
        float w10 = (vy1 && vx0) ? m * ly * hx : 0.f;
        float w11 = (vy1 && vx1) ? m * ly * lx : 0.f;
        int y0c = min(max(y0, 0), Hs - 1), y1c = min(max(y1, 0), Hs - 1);
        int x0c = min(max(x0, 0), Ws - 1), x1c = min(max(x1, 0), Ws - 1);
        int o00 = y0c * Ws + x0c, o01 = y0c * Ws + x1c;
        int o10 = y1c * Ws + x0c, o11 = y1c * Ws + x1c;
        const float* xp = xb + (g * 16) * PLANE;
        float* sp = &lds[SMP_OFF + bufi * 4096 + (g * 16) * 64 + px];
#pragma unroll
        for (int i = 0; i < 16; ++i) {
            float v = xp[o00] * w00 + xp[o01] * w01 + xp[o10] * w10 + xp[o11] * w11;
            sp[i * 64] = v;
            xp += PLANE;
        }
    };

    // prologue: wls(tap0) + smp(tap0)
    {
        const float4* srcw = (const float4*)(wT);
        float4* dstw = (float4*)&lds[WLS_OFF];
#pragma unroll
        for (int j = 0; j < 4; ++j) dstw[tid + 256 * j] = srcw[tid + 256 * j];
    }
    __syncthreads();   // om_s complete + A-weight reads done before smp overwrites region
    stage_smp(0, 0);
    __syncthreads();

    float wreg[16];
#pragma unroll 1
    for (int k = 0; k < KK; ++k) {
        if (k + 1 < KK) {   // prefetch next tap's weights into registers
            const float4* srcw = (const float4*)(wT + (k + 1) * 4096);
#pragma unroll
            for (int j = 0; j < 4; ++j) ((float4*)wreg)[j] = srcw[tid + 256 * j];
            stage_smp(k + 1, (k + 1) & 1);   // gathers overlap FMA below
        }
        {   // FMA tap k
            const float* smpb = &lds[SMP_OFF + (k & 1) * 4096];
            const float* wp   = &lds[WLS_OFF + g * 16];
#pragma unroll 4
            for (int c = 0; c < 64; ++c) {
                float s = smpb[c * 64 + px];
                const float4* w4 = (const float4*)(wp + c * 64);  // broadcast b128
                float4 a0 = w4[0], a1 = w4[1], a2 = w4[2], a3 = w4[3];
                acc[0]  = fmaf(s, a0.x, acc[0]);  acc[1]  = fmaf(s, a0.y, acc[1]);
                acc[2]  = fmaf(s, a0.z, acc[2]);  acc[3]  = fmaf(s, a0.w, acc[3]);
                acc[4]  = fmaf(s, a1.x, acc[4]);  acc[5]  = fmaf(s, a1.y, acc[5]);
                acc[6]  = fmaf(s, a1.z, acc[6]);  acc[7]  = fmaf(s, a1.w, acc[7]);
                acc[8]  = fmaf(s, a2.x, acc[8]);  acc[9]  = fmaf(s, a2.y, acc[9]);
                acc[10] = fmaf(s, a2.z, acc[10]); acc[11] = fmaf(s, a2.w, acc[11]);
                acc[12] = fmaf(s, a3.x, acc[12]); acc[13] = fmaf(s, a3.y, acc[13]);
                acc[14] = fmaf(s, a3.z, acc[14]); acc[15] = fmaf(s, a3.w, acc[15]);
            }
        }
        __syncthreads();                 // fma(k) done; smp(k+1) writes drained
        if (k + 1 < KK) {                // refresh wls from registers (cheap)
            float4* dstw = (float4*)&lds[WLS_OFF];
#pragma unroll
            for (int j = 0; j < 4; ++j) dstw[tid + 256 * j] = ((float4*)wreg)[j];
            __syncthreads();
        }
    }

    int obase = b * (COUT_ * PLANE) + (g * 16) * PLANE + r;
#pragma unroll
    for (int j = 0; j < 16; ++j)
        out[obase + j * PLANE] = acc[j];   // coalesced
}

extern "C" void kernel_launch(void* const* d_in, const int* in_sizes, int n_in,
                              void* d_out, int out_size, void* d_ws, size_t ws_size,
                              hipStream_t stream) {
    const float* x      = (const float*)d_in[0];
    const float* w_off  = (const float*)d_in[1];
    const float* b_off  = (const float*)d_in[2];
    const float* weight = (const float*)d_in[3];
    const float* bias   = (const float*)d_in[4];
    float* out = (float*)d_out;

    char* ws = (char*)d_ws;
    float* wT   = (float*)ws;                 // 147456 B
    float* woA2 = (float*)(ws + 0x24000);     //  65536 B

    transpose_weights<<<144, 256, 0, stream>>>(weight, w_off, wT, woA2);
    deform_all<<<NBLK, 256, 0, stream>>>(x, woA2, b_off, wT, bias, out);
}

// Round 5
// 213.329 us; speedup vs baseline: 2.4041x; 2.4041x over previous
//
#include <hip/hip_runtime.h>
#include <math.h>

typedef __bf16 b16x8 __attribute__((ext_vector_type(8)));
typedef float  f32x4 __attribute__((ext_vector_type(4)));

#define B_    8
#define CIN_  64
#define COUT_ 64
#define Hs    96
#define Ws    96
#define PLANE (Hs*Ws)        // 9216
#define IMG   (CIN_*PLANE)   // 589824
#define NP    (B_*PLANE)     // 73728
#define NBLK  (NP/64)        // 1152

__device__ __forceinline__ int swz(int bid) { return (bid & 7) * (NBLK / 8) + (bid >> 3); }

// Pre-swizzle weights into per-lane MFMA A-fragment order (bf16).
// wAB flat: i = k*4096 + ks*2048 + mt*512 + lane*8 + e
//   o = mt*16 + (lane&15); c = ks*32 + (lane>>4)*8 + e; val = weight[o*576 + c*9 + k]
// wAO flat: j = t*2048 + ks*1024 + mt*512 + lane*8 + e
//   ch = mt*16 + (lane&15); c likewise; val = w_off[ch*576 + c*9 + t] (0 for ch>=27)
__global__ void prep(const float* __restrict__ weight, const float* __restrict__ w_off,
                     __bf16* __restrict__ wAB, __bf16* __restrict__ wAO) {
    int i = blockIdx.x * 256 + threadIdx.x;
    if (i < 36864) {
        int e = i & 7, lane = (i >> 3) & 63, mt = (i >> 9) & 3, ks = (i >> 11) & 1, k = i >> 12;
        int o = mt * 16 + (lane & 15);
        int c = ks * 32 + ((lane >> 4) << 3) + e;
        wAB[i] = (__bf16)weight[o * 576 + c * 9 + k];
    }
    if (i < 18432) {
        int e = i & 7, lane = (i >> 3) & 63, mt = (i >> 9) & 1, ks = (i >> 10) & 1, t = i >> 11;
        int ch = mt * 16 + (lane & 15);
        int c  = ks * 32 + ((lane >> 4) << 3) + e;
        wAO[i] = (ch < 27) ? (__bf16)w_off[ch * 576 + c * 9 + t] : (__bf16)(0.f);
    }
}

// One fused kernel. Block = 64 px x 4 waves.
// Phase A: om[27][64] via MFMA (M=32 padded, K=576), result -> LDS.
// Phase B: main conv via MFMA (M=64, K=576), sampled bf16 tile in dbuf LDS.
// B-tile layout: sS[buf][px][c] with row stride 72 bf16 (pad 8 -> 16B-aligned frags).
__global__ __launch_bounds__(256)
void deform_mfma(const float* __restrict__ x,
                 const __bf16* __restrict__ wAO,
                 const float* __restrict__ b_off,
                 const __bf16* __restrict__ wAB,
                 const float* __restrict__ bias,
                 float* __restrict__ out) {
    __shared__ __align__(16) __bf16 sS[2 * 4608];   // 18432 B
    __shared__ float omL[27 * 64];                  //  6912 B

    int tid  = threadIdx.x;
    int lane = tid & 63;
    int px   = lane;
    int g    = __builtin_amdgcn_readfirstlane(tid >> 6);
    int n    = lane & 15;
    int kg   = lane >> 4;

    int pg0  = swz(blockIdx.x) * 64;
    int b    = pg0 / PLANE;
    int rblk = pg0 - b * PLANE;
    int rr   = rblk + px;
    int h    = rr / Ws, w = rr - h * Ws;
    const float* xb = x + b * IMG;
    const float* xg = xb + (g * 16) * PLANE;   // this wave stages c = g*16 .. g*16+15

    const b16x8* wAOv = (const b16x8*)wAO;
    const b16x8* wABv = (const b16x8*)wAB;

    // ---------------- Phase A: offset conv via MFMA ----------------
    f32x4 accA0 = {0.f, 0.f, 0.f, 0.f};
    f32x4 accA1 = {0.f, 0.f, 0.f, 0.f};
#pragma unroll 1
    for (int t = 0; t < 9; ++t) {
        // A-fragments (issued early; latency hidden by staging below)
        b16x8 af0 = wAOv[((t * 2 + 0) * 2 + 0) * 64 + lane];
        b16x8 af1 = wAOv[((t * 2 + 0) * 2 + 1) * 64 + lane];
        b16x8 af2 = wAOv[((t * 2 + 1) * 2 + 0) * 64 + lane];
        b16x8 af3 = wAOv[((t * 2 + 1) * 2 + 1) * 64 + lane];

        // stage x-patch tile (zero-padded) as bf16 [px][c]
        int ky = t / 3, kx = t - ky * 3;
        int yy = h - 1 + ky, xx = w - 1 + kx;
        float msk = (yy >= 0 && yy < Hs && xx >= 0 && xx < Ws) ? 1.f : 0.f;
        int idx = min(max(yy, 0), Hs - 1) * Ws + min(max(xx, 0), Ws - 1);
        const float* xp = xg + idx;
        b16x8 v0, v1;
#pragma unroll
        for (int i = 0; i < 8; ++i) v0[i] = (__bf16)(xp[i * PLANE] * msk);
#pragma unroll
        for (int i = 0; i < 8; ++i) v1[i] = (__bf16)(xp[(i + 8) * PLANE] * msk);
        int wb = (t & 1) * 4608 + px * 72 + g * 16;
        *(b16x8*)&sS[wb]     = v0;
        *(b16x8*)&sS[wb + 8] = v1;
        __syncthreads();

        int rbase = (t & 1) * 4608 + (g * 16 + n) * 72 + kg * 8;
        b16x8 bf0 = *(const b16x8*)&sS[rbase];
        b16x8 bf1 = *(const b16x8*)&sS[rbase + 32];
        accA0 = __builtin_amdgcn_mfma_f32_16x16x32_bf16(af0, bf0, accA0, 0, 0, 0);
        accA1 = __builtin_amdgcn_mfma_f32_16x16x32_bf16(af1, bf0, accA1, 0, 0, 0);
        accA0 = __builtin_amdgcn_mfma_f32_16x16x32_bf16(af2, bf1, accA0, 0, 0, 0);
        accA1 = __builtin_amdgcn_mfma_f32_16x16x32_bf16(af3, bf1, accA1, 0, 0, 0);
    }
    // write om (+b_off) to LDS: C layout row=(kg*4+r), col=n
#pragma unroll
    for (int rg = 0; rg < 4; ++rg) {
        int ch = kg * 4 + rg;
        omL[ch * 64 + g * 16 + n] = accA0[rg] + b_off[ch];
    }
#pragma unroll
    for (int rg = 0; rg < 4; ++rg) {
        int ch = 16 + kg * 4 + rg;
        if (ch < 27) omL[ch * 64 + g * 16 + n] = accA1[rg] + b_off[ch];
    }
    __syncthreads();

    // ---------------- Phase B: sampling + main conv via MFMA ----------------
    f32x4 acc0 = {0.f, 0.f, 0.f, 0.f};
    f32x4 acc1 = {0.f, 0.f, 0.f, 0.f};
    f32x4 acc2 = {0.f, 0.f, 0.f, 0.f};
    f32x4 acc3 = {0.f, 0.f, 0.f, 0.f};
#pragma unroll 1
    for (int k = 0; k < 9; ++k) {
        b16x8 a0 = wABv[(k * 8 + 0) * 64 + lane];   // ks0, mt0..3
        b16x8 a1 = wABv[(k * 8 + 1) * 64 + lane];
        b16x8 a2 = wABv[(k * 8 + 2) * 64 + lane];
        b16x8 a3 = wABv[(k * 8 + 3) * 64 + lane];
        b16x8 a4 = wABv[(k * 8 + 4) * 64 + lane];   // ks1, mt0..3
        b16x8 a5 = wABv[(k * 8 + 5) * 64 + lane];
        b16x8 a6 = wABv[(k * 8 + 6) * 64 + lane];
        b16x8 a7 = wABv[(k * 8 + 7) * 64 + lane];

        float dy = omL[(2 * k) * 64 + px];
        float dx = omL[(2 * k + 1) * 64 + px];
        float mo = omL[(18 + k) * 64 + px];
        float m  = 1.f / (1.f + __expf(-mo));
        int ky = k / 3, kx = k - ky * 3;
        float ys = (float)(h - 1 + ky) + dy;
        float xs = (float)(w - 1 + kx) + dx;
        float y0f = floorf(ys), x0f = floorf(xs);
        float ly = ys - y0f, lx = xs - x0f;
        float hy = 1.f - ly, hx = 1.f - lx;
        int y0 = (int)y0f, x0 = (int)x0f;
        int y1 = y0 + 1, x1 = x0 + 1;
        bool vy0 = (y0 >= 0) && (y0 < Hs);
        bool vy1 = (y1 >= 0) && (y1 < Hs);
        bool vx0 = (x0 >= 0) && (x0 < Ws);
        bool vx1 = (x1 >= 0) && (x1 < Ws);
        float w00 = (vy0 && vx0) ? m * hy * hx : 0.f;
        float w01 = (vy0 && vx1) ? m * hy * lx : 0.f;
        float w10 = (vy1 && vx0) ? m * ly * hx : 0.f;
        float w11 = (vy1 && vx1) ? m * ly * lx : 0.f;
        int y0c = min(max(y0, 0), Hs - 1), y1c = min(max(y1, 0), Hs - 1);
        int x0c = min(max(x0, 0), Ws - 1), x1c = min(max(x1, 0), Ws - 1);
        int o00 = y0c * Ws + x0c, o01 = y0c * Ws + x1c;
        int o10 = y1c * Ws + x0c, o11 = y1c * Ws + x1c;

        const float* xp = xg;
        b16x8 v0, v1;
#pragma unroll
        for (int i = 0; i < 16; ++i) {
            float vv = xp[o00] * w00 + xp[o01] * w01 + xp[o10] * w10 + xp[o11] * w11;
            if (i < 8) v0[i] = (__bf16)vv; else v1[i - 8] = (__bf16)vv;
            xp += PLANE;
        }
        int wb = (k & 1) * 4608 + px * 72 + g * 16;
        *(b16x8*)&sS[wb]     = v0;
        *(b16x8*)&sS[wb + 8] = v1;
        __syncthreads();

        int rbase = (k & 1) * 4608 + (g * 16 + n) * 72 + kg * 8;
        b16x8 bf0 = *(const b16x8*)&sS[rbase];
        b16x8 bf1 = *(const b16x8*)&sS[rbase + 32];
        acc0 = __builtin_amdgcn_mfma_f32_16x16x32_bf16(a0, bf0, acc0, 0, 0, 0);
        acc1 = __builtin_amdgcn_mfma_f32_16x16x32_bf16(a1, bf0, acc1, 0, 0, 0);
        acc2 = __builtin_amdgcn_mfma_f32_16x16x32_bf16(a2, bf0, acc2, 0, 0, 0);
        acc3 = __builtin_amdgcn_mfma_f32_16x16x32_bf16(a3, bf0, acc3, 0, 0, 0);
        acc0 = __builtin_amdgcn_mfma_f32_16x16x32_bf16(a4, bf1, acc0, 0, 0, 0);
        acc1 = __builtin_amdgcn_mfma_f32_16x16x32_bf16(a5, bf1, acc1, 0, 0, 0);
        acc2 = __builtin_amdgcn_mfma_f32_16x16x32_bf16(a6, bf1, acc2, 0, 0, 0);
        acc3 = __builtin_amdgcn_mfma_f32_16x16x32_bf16(a7, bf1, acc3, 0, 0, 0);
    }

    // epilogue: C layout row=o-within-tile=(kg*4+r), col=n -> px strip g*16+n
    int ob = b * (COUT_ * PLANE) + rblk + g * 16 + n;
#pragma unroll
    for (int rg = 0; rg < 4; ++rg) { int o =      kg * 4 + rg; out[ob + o * PLANE] = acc0[rg] + bias[o]; }
#pragma unroll
    for (int rg = 0; rg < 4; ++rg) { int o = 16 + kg * 4 + rg; out[ob + o * PLANE] = acc1[rg] + bias[o]; }
#pragma unroll
    for (int rg = 0; rg < 4; ++rg) { int o = 32 + kg * 4 + rg; out[ob + o * PLANE] = acc2[rg] + bias[o]; }
#pragma unroll
    for (int rg = 0; rg < 4; ++rg) { int o = 48 + kg * 4 + rg; out[ob + o * PLANE] = acc3[rg] + bias[o]; }
}

extern "C" void kernel_launch(void* const* d_in, const int* in_sizes, int n_in,
                              void* d_out, int out_size, void* d_ws, size_t ws_size,
                              hipStream_t stream) {
    const float* x      = (const float*)d_in[0];
    const float* w_off  = (const float*)d_in[1];
    const float* b_off  = (const float*)d_in[2];
    const float* weight = (const float*)d_in[3];
    const float* bias   = (const float*)d_in[4];
    float* out = (float*)d_out;

    char* ws = (char*)d_ws;
    __bf16* wAB = (__bf16*)ws;             // 73728 B
    __bf16* wAO = (__bf16*)(ws + 73728);   // 36864 B

    prep<<<144, 256, 0, stream>>>(weight, w_off, wAB, wAO);
    deform_mfma<<<NBLK, 256, 0, stream>>>(x, wAO, b_off, wAB, bias, out);
}